// Round 2
// baseline (335.157 us; speedup 1.0000x reference)
//
#include <hip/hip_runtime.h>
#include <math.h>

#define B_    32
#define H_    32
#define KVH_  8
#define D_    128
#define HID_  4096
#define TPB_  64
#define MB_   32
#define G_    4
#define RQKV  6144
#define KS_   16
#define NCH   8
#define SCALING 0.08838834764831845f

typedef __attribute__((ext_vector_type(8))) short short8_t;
typedef __attribute__((ext_vector_type(16))) float f32x16;

// pack two small-int-valued floats into a bf16 pair (exact for |v|<=127 integers)
__device__ __forceinline__ unsigned int pk2(float lo, float hi) {
  return (__float_as_uint(hi) & 0xffff0000u) | (__float_as_uint(lo) >> 16);
}

// ---------- build X B-fragments from hidden_q (int [32][4096]) ----------
// frag tile t (16 k), lane l: elems e=0..7 = X^T[16t + 8*(l>>5)+e][l&31]
__global__ __launch_bounds__(256) void kprep_x(const int* __restrict__ src, uint4* __restrict__ frag) {
  int gid = blockIdx.x * 256 + threadIdx.x;   // 256 tiles * 64 lanes = 16384
  int l = gid & 63, t = gid >> 6;
  int bb = l & 31;
  int k0 = t * 16 + (l >> 5) * 8;
  const int* p = &src[(size_t)bb * HID_ + k0];
  int4 a = *(const int4*)p;
  int4 c = *(const int4*)(p + 4);
  uint4 o;
  o.x = pk2((float)a.x, (float)a.y);
  o.y = pk2((float)a.z, (float)a.w);
  o.z = pk2((float)c.x, (float)c.y);
  o.w = pk2((float)c.z, (float)c.w);
  frag[gid] = o;
}

// ---------- build X B-fragments from aqT (float [4096][32], small ints) ----------
__global__ __launch_bounds__(256) void kprep_a(const float* __restrict__ src, uint4* __restrict__ frag) {
  int gid = blockIdx.x * 256 + threadIdx.x;
  int l = gid & 63, t = gid >> 6;
  int bb = l & 31;
  int k0 = t * 16 + (l >> 5) * 8;
  float v[8];
#pragma unroll
  for (int e = 0; e < 8; e++) v[e] = src[(size_t)(k0 + e) * 32 + bb];
  uint4 o;
  o.x = pk2(v[0], v[1]);
  o.y = pk2(v[2], v[3]);
  o.z = pk2(v[4], v[5]);
  o.w = pk2(v[6], v[7]);
  frag[gid] = o;
}

// ---------- MFMA GEMM: Yp[ks][R][32] = W[R][4096] x X^T[4096][32] (k-split 16) ----------
// block 256 thr = 4 waves; wave -> 32x32 output tile; per block 128 rows, 256-k window
__global__ __launch_bounds__(256) void kgemm_mfma(const int* __restrict__ W, const uint4* __restrict__ xf,
                                                  float* __restrict__ Yp, int R) {
  int wave = threadIdx.x >> 6, lane = threadIdx.x & 63;
  int j0 = blockIdx.x * 128 + wave * 32;
  int row = lane & 31, hi = lane >> 5;
  int kbase = blockIdx.y * 256;
  f32x16 acc;
#pragma unroll
  for (int i = 0; i < 16; i++) acc[i] = 0.f;
  const int* wp = &W[(size_t)(j0 + row) * HID_ + kbase + hi * 8];
  const uint4* xp = &xf[(size_t)(kbase >> 4) * 64 + lane];
#pragma unroll
  for (int t = 0; t < 16; t++) {
    int4 wa = *(const int4*)(wp + t * 16);
    int4 wb = *(const int4*)(wp + t * 16 + 4);
    uint4 aw;
    aw.x = pk2((float)wa.x, (float)wa.y);
    aw.y = pk2((float)wa.z, (float)wa.w);
    aw.z = pk2((float)wb.x, (float)wb.y);
    aw.w = pk2((float)wb.z, (float)wb.w);
    uint4 bw = xp[t * 64];
    acc = __builtin_amdgcn_mfma_f32_32x32x16_bf16(__builtin_bit_cast(short8_t, aw),
                                                  __builtin_bit_cast(short8_t, bw), acc, 0, 0, 0);
  }
  int col = lane & 31;
#pragma unroll
  for (int r = 0; r < 16; r++) {
    int rowout = (r & 3) + 8 * (r >> 2) + 4 * hi;
    Yp[((size_t)blockIdx.y * R + j0 + rowout) * 32 + col] = acc[r];
  }
}

// ---------- k1b: reduce partials + scales + RoPE + fresh k/v quant ----------
__global__ __launch_bounds__(128) void kpost_qkv(const float* __restrict__ Yp, const float* __restrict__ hs,
                                                 const float* __restrict__ wsc, const int* __restrict__ ctx,
                                                 float* __restrict__ qrope, int* __restrict__ kqf,
                                                 int* __restrict__ vqf, float* __restrict__ ksf,
                                                 float* __restrict__ vsf) {
  int r = blockIdx.x;      // 0..47
  int b = blockIdx.y;      // 0..31
  int d = threadIdx.x;     // 0..127
  int j = r * 128 + d;
  float v = 0.f;
#pragma unroll
  for (int ks = 0; ks < KS_; ks++) v += Yp[((size_t)ks * RQKV + j) * 32 + b];
  v *= hs[b] * wsc[j];
  __shared__ float x[128];
  __shared__ float red[2];
  x[d] = v;
  __syncthreads();
  int pos = ctx[b];
  float val;
  if (r < 40) {
    int i = d & 63;
    float f = powf(10000.f, -(float)i * (1.f / 64.f));
    float ang = (float)pos * f;
    float sv, cv;
    sincosf(ang, &sv, &cv);
    float xa = x[i], xb = x[i + 64];
    val = (d < 64) ? (xa * cv - xb * sv) : (xb * cv + xa * sv);
  } else {
    val = v;
  }
  if (r < 32) { qrope[((size_t)b * H_ + r) * D_ + d] = val; return; }
  float a = fabsf(val);
#pragma unroll
  for (int off = 32; off; off >>= 1) a = fmaxf(a, __shfl_xor(a, off));
  if ((d & 63) == 0) red[d >> 6] = a;
  __syncthreads();
  float mx = fmaxf(red[0], red[1]);
  float sc = fmaxf(mx, 1e-6f) * (1.f / 127.f);
  float qv = rintf(val / sc);
  qv = fminf(fmaxf(qv, -127.f), 127.f);
  int kvh = (r - 32) & 7;
  if (r < 40) {
    kqf[((size_t)b * KVH_ + kvh) * D_ + d] = (int)qv;
    if (d == 0) ksf[b * KVH_ + kvh] = sc;
  } else {
    vqf[((size_t)b * KVH_ + kvh) * D_ + d] = (int)qv;
    if (d == 0) vsf[b * KVH_ + kvh] = sc;
  }
}

// ---------- fresh-token score ----------
__global__ __launch_bounds__(64) void kfresh_score(const float* __restrict__ qrope, const int* __restrict__ kqf,
                                                   const float* __restrict__ ksf, float* __restrict__ qkf) {
  int h = blockIdx.x, b = blockIdx.y, l = threadIdx.x;
  int kvh = h >> 2;
  const float* q = &qrope[((size_t)b * H_ + h) * D_];
  const int* kk = &kqf[((size_t)b * KVH_ + kvh) * D_];
  float s = q[l] * (float)kk[l] + q[l + 64] * (float)kk[l + 64];
#pragma unroll
  for (int off = 32; off; off >>= 1) s += __shfl_xor(s, off);
  if (l == 0) qkf[b * H_ + h] = s * ksf[b * KVH_ + kvh] * SCALING;
}

// ---------- flash-decoding attention, 256-token chunks ----------
__global__ __launch_bounds__(256) void kattn(const int* __restrict__ kvc, const float* __restrict__ kvs,
                                             const int* __restrict__ btab, const int* __restrict__ ctx,
                                             const float* __restrict__ qrope, const float* __restrict__ qkf,
                                             const int* __restrict__ vqf, const float* __restrict__ vsf,
                                             float* __restrict__ pm, float* __restrict__ pl,
                                             float* __restrict__ pacc) {
  int ch = blockIdx.x, kvh = blockIdx.y, b = blockIdx.z;
  int tid = threadIdx.x;
  int pos = ctx[b];
  int s0 = ch * 256;
  size_t pbase = ((size_t)(b * KVH_ + kvh) * NCH + ch) * G_;
  if (s0 > pos) {
    if (tid < 4) { pm[pbase + tid] = -1e30f; pl[pbase + tid] = 0.f; }
    return;
  }
  __shared__ __align__(16) float qlds[512];
  __shared__ __align__(16) float plds[1024];
  __shared__ float rbuf[4][4];
  for (int i = tid; i < 512; i += 256) qlds[i] = qrope[((size_t)b * H_ + kvh * G_) * D_ + i];
  __syncthreads();

  int s = s0 + tid;
  bool cached = (s < pos);
  bool isfresh = (s == pos);
  bool valid = cached || isfresh;
  float sc0 = 0.f, sc1 = 0.f, sc2 = 0.f, sc3 = 0.f;
  if (cached) {
    int blk = btab[b * MB_ + (s >> 6)];
    int within = s & 63;
    const int* krow = &kvc[(((size_t)(blk * 2 + 0) * KVH_ + kvh) * TPB_ + within) * D_];
    float ksc = kvs[((size_t)(blk * 2 + 0) * KVH_ + kvh) * TPB_ + within];
#pragma unroll 8
    for (int d0 = 0; d0 < 128; d0 += 4) {
      int4 kk = *(const int4*)&krow[d0];
      float k0 = (float)kk.x, k1 = (float)kk.y, k2v = (float)kk.z, k3 = (float)kk.w;
      float4 q0 = *(const float4*)&qlds[0 * 128 + d0];
      float4 q1 = *(const float4*)&qlds[1 * 128 + d0];
      float4 q2 = *(const float4*)&qlds[2 * 128 + d0];
      float4 q3 = *(const float4*)&qlds[3 * 128 + d0];
      sc0 += q0.x * k0 + q0.y * k1 + q0.z * k2v + q0.w * k3;
      sc1 += q1.x * k0 + q1.y * k1 + q1.z * k2v + q1.w * k3;
      sc2 += q2.x * k0 + q2.y * k1 + q2.z * k2v + q2.w * k3;
      sc3 += q3.x * k0 + q3.y * k1 + q3.z * k2v + q3.w * k3;
    }
    float m = ksc * SCALING;
    sc0 *= m; sc1 *= m; sc2 *= m; sc3 *= m;
  } else if (isfresh) {
    sc0 = qkf[b * H_ + kvh * G_ + 0];
    sc1 = qkf[b * H_ + kvh * G_ + 1];
    sc2 = qkf[b * H_ + kvh * G_ + 2];
    sc3 = qkf[b * H_ + kvh * G_ + 3];
  }
  int wave = tid >> 6, lane = tid & 63;
  float v0 = valid ? sc0 : -1e30f, v1 = valid ? sc1 : -1e30f;
  float v2 = valid ? sc2 : -1e30f, v3 = valid ? sc3 : -1e30f;
#pragma unroll
  for (int off = 32; off; off >>= 1) {
    v0 = fmaxf(v0, __shfl_xor(v0, off));
    v1 = fmaxf(v1, __shfl_xor(v1, off));
    v2 = fmaxf(v2, __shfl_xor(v2, off));
    v3 = fmaxf(v3, __shfl_xor(v3, off));
  }
  if (lane == 0) { rbuf[wave][0] = v0; rbuf[wave][1] = v1; rbuf[wave][2] = v2; rbuf[wave][3] = v3; }
  __syncthreads();
  float m0 = fmaxf(fmaxf(rbuf[0][0], rbuf[1][0]), fmaxf(rbuf[2][0], rbuf[3][0]));
  float m1 = fmaxf(fmaxf(rbuf[0][1], rbuf[1][1]), fmaxf(rbuf[2][1], rbuf[3][1]));
  float m2 = fmaxf(fmaxf(rbuf[0][2], rbuf[1][2]), fmaxf(rbuf[2][2], rbuf[3][2]));
  float m3 = fmaxf(fmaxf(rbuf[0][3], rbuf[1][3]), fmaxf(rbuf[2][3], rbuf[3][3]));
  float p0 = valid ? expf(sc0 - m0) : 0.f;
  float p1 = valid ? expf(sc1 - m1) : 0.f;
  float p2 = valid ? expf(sc2 - m2) : 0.f;
  float p3 = valid ? expf(sc3 - m3) : 0.f;
  float t0 = p0, t1 = p1, t2 = p2, t3 = p3;
#pragma unroll
  for (int off = 32; off; off >>= 1) {
    t0 += __shfl_xor(t0, off);
    t1 += __shfl_xor(t1, off);
    t2 += __shfl_xor(t2, off);
    t3 += __shfl_xor(t3, off);
  }
  __syncthreads();
  if (lane == 0) { rbuf[wave][0] = t0; rbuf[wave][1] = t1; rbuf[wave][2] = t2; rbuf[wave][3] = t3; }
  __syncthreads();
  if (tid == 0) {
    pm[pbase + 0] = m0; pm[pbase + 1] = m1; pm[pbase + 2] = m2; pm[pbase + 3] = m3;
    pl[pbase + 0] = rbuf[0][0] + rbuf[1][0] + rbuf[2][0] + rbuf[3][0];
    pl[pbase + 1] = rbuf[0][1] + rbuf[1][1] + rbuf[2][1] + rbuf[3][1];
    pl[pbase + 2] = rbuf[0][2] + rbuf[1][2] + rbuf[2][2] + rbuf[3][2];
    pl[pbase + 3] = rbuf[0][3] + rbuf[1][3] + rbuf[2][3] + rbuf[3][3];
  }
  float vsc = 0.f;
  if (cached) {
    int blk = btab[b * MB_ + (s >> 6)];
    vsc = kvs[((size_t)(blk * 2 + 1) * KVH_ + kvh) * TPB_ + (s & 63)];
  } else if (isfresh) {
    vsc = vsf[b * KVH_ + kvh];
  }
  plds[tid * 4 + 0] = p0 * vsc;
  plds[tid * 4 + 1] = p1 * vsc;
  plds[tid * 4 + 2] = p2 * vsc;
  plds[tid * 4 + 3] = p3 * vsc;
  __syncthreads();
  // PV: 4 static cache-block sub-loops; fresh token added after
  int ncv = min(256, pos - s0);          // cached tokens in this chunk
  int dloc = (wave << 5) + (lane & 31);
  int half = lane >> 5;
  float a0 = 0.f, a1 = 0.f, a2 = 0.f, a3 = 0.f;
#pragma unroll
  for (int cb = 0; cb < 4; cb++) {
    int t0b = cb * 64;
    int nt = min(64, ncv - t0b);
    if (nt > 0) {
      int blk = btab[b * MB_ + (s0 >> 6) + cb];
      const int* vb = &kvc[(((size_t)(blk * 2 + 1) * KVH_ + kvh) * TPB_) * D_ + dloc];
      for (int tt = half; tt < nt; tt += 2) {
        float vv = (float)vb[(size_t)tt * D_];
        float4 pp = *(const float4*)&plds[(t0b + tt) * 4];
        a0 = fmaf(pp.x, vv, a0);
        a1 = fmaf(pp.y, vv, a1);
        a2 = fmaf(pp.z, vv, a2);
        a3 = fmaf(pp.w, vv, a3);
      }
    }
  }
  if (ncv < 256 && half == 0) {          // fresh token at slot ncv
    float vv = (float)vqf[(size_t)(b * KVH_ + kvh) * D_ + dloc];
    float4 pp = *(const float4*)&plds[ncv * 4];
    a0 = fmaf(pp.x, vv, a0);
    a1 = fmaf(pp.y, vv, a1);
    a2 = fmaf(pp.z, vv, a2);
    a3 = fmaf(pp.w, vv, a3);
  }
  a0 += __shfl_xor(a0, 32);
  a1 += __shfl_xor(a1, 32);
  a2 += __shfl_xor(a2, 32);
  a3 += __shfl_xor(a3, 32);
  if (half == 0) {
    float* pa = &pacc[pbase * D_];
    pa[0 * D_ + dloc] = a0;
    pa[1 * D_ + dloc] = a1;
    pa[2 * D_ + dloc] = a2;
    pa[3 * D_ + dloc] = a3;
  }
}

// ---------- combine chunks + per-batch quantize ----------
__global__ __launch_bounds__(256) void kcomb_quant(const float* __restrict__ pm, const float* __restrict__ pl,
                                                   const float* __restrict__ pacc, float* __restrict__ aqT,
                                                   float* __restrict__ asb) {
  int b = blockIdx.x;
  int tid = threadIdx.x;
  __shared__ float wch[32][8];
  __shared__ float invL[32];
  __shared__ float rbuf2[4];
  if (tid < 32) {
    int kvh = tid >> 2, g = tid & 3;
    float m[8], lv[8];
    float M = -1e30f;
#pragma unroll
    for (int ch = 0; ch < 8; ch++) {
      size_t pb = ((size_t)(b * KVH_ + kvh) * NCH + ch) * G_ + g;
      m[ch] = pm[pb];
      lv[ch] = pl[pb];
      M = fmaxf(M, m[ch]);
    }
    float L = 0.f;
#pragma unroll
    for (int ch = 0; ch < 8; ch++) {
      float w = expf(m[ch] - M);
      wch[tid][ch] = w;
      L += lv[ch] * w;
    }
    invL[tid] = 1.f / L;
  }
  __syncthreads();
  float vals[16];
  float amax = 0.f;
#pragma unroll
  for (int i = 0; i < 16; i++) {
    int j = i * 256 + tid;
    int h = j >> 7, d = j & 127;
    int kvh = h >> 2, g = h & 3;
    float v = 0.f;
#pragma unroll
    for (int ch = 0; ch < 8; ch++) {
      v += pacc[(((size_t)(b * KVH_ + kvh) * NCH + ch) * G_ + g) * D_ + d] * wch[h][ch];
    }
    v *= invL[h];
    vals[i] = v;
    amax = fmaxf(amax, fabsf(v));
  }
#pragma unroll
  for (int off = 32; off; off >>= 1) amax = fmaxf(amax, __shfl_xor(amax, off));
  if ((tid & 63) == 0) rbuf2[tid >> 6] = amax;
  __syncthreads();
  amax = fmaxf(fmaxf(rbuf2[0], rbuf2[1]), fmaxf(rbuf2[2], rbuf2[3]));
  float as = fmaxf(amax, 1e-6f) * (1.f / 127.f);
#pragma unroll
  for (int i = 0; i < 16; i++) {
    int j = i * 256 + tid;
    float qv = rintf(vals[i] / as);
    qv = fminf(fmaxf(qv, -127.f), 127.f);
    aqT[(size_t)j * 32 + b] = qv;
  }
  if (tid == 0) asb[b] = as;
}

// ---------- reduce o-proj partials + final scales ----------
__global__ __launch_bounds__(256) void kfinal(const float* __restrict__ Yp, const float* __restrict__ asb,
                                              const float* __restrict__ owsc, float* __restrict__ out) {
  int gid = blockIdx.x * 256 + threadIdx.x;   // 131072
  int i = gid & (HID_ - 1), bb = gid >> 12;
  float v = 0.f;
#pragma unroll
  for (int ks = 0; ks < KS_; ks++) v += Yp[((size_t)ks * HID_ + i) * 32 + bb];
  out[(size_t)bb * HID_ + i] = v * asb[bb] * owsc[i];
}

extern "C" void kernel_launch(void* const* d_in, const int* in_sizes, int n_in,
                              void* d_out, int out_size, void* d_ws, size_t ws_size,
                              hipStream_t stream) {
  const int*   hq    = (const int*)d_in[0];
  const float* hs    = (const float*)d_in[1];
  const int*   qkvw  = (const int*)d_in[2];
  const float* qkvws = (const float*)d_in[3];
  const int*   ow    = (const int*)d_in[4];
  const float* owsc  = (const float*)d_in[5];
  const int*   kvc   = (const int*)d_in[6];
  const float* kvs   = (const float*)d_in[7];
  const int*   btab  = (const int*)d_in[8];
  const int*   ctx   = (const int*)d_in[9];
  float* out = (float*)d_out;

  char* ws = (char*)d_ws;
  uint4* xf    = (uint4*)(ws);                 // 262144
  uint4* af    = (uint4*)(ws + 262144);        // 262144
  float* Yp    = (float*)(ws + 524288);        // 12582912 (qkv; reused for o-proj)
  float* qrope = (float*)(ws + 13107200);      // 524288
  int*   kqf   = (int*)  (ws + 13631488);      // 131072
  int*   vqf   = (int*)  (ws + 13762560);      // 131072
  float* ksf   = (float*)(ws + 13893632);      // 1024
  float* vsf   = (float*)(ws + 13894656);      // 1024
  float* qkf   = (float*)(ws + 13895680);      // 4096
  float* pm    = (float*)(ws + 13899776);      // 32768
  float* pl    = (float*)(ws + 13932544);      // 32768
  float* pacc  = (float*)(ws + 13965312);      // 4194304
  float* aqT   = (float*)(ws + 18159616);      // 524288
  float* asb   = (float*)(ws + 18683904);      // 128

  kprep_x<<<64, 256, 0, stream>>>(hq, xf);
  kgemm_mfma<<<dim3(RQKV / 128, KS_), 256, 0, stream>>>(qkvw, xf, Yp, RQKV);
  kpost_qkv<<<dim3(48, 32), 128, 0, stream>>>(Yp, hs, qkvws, ctx, qrope, kqf, vqf, ksf, vsf);
  kfresh_score<<<dim3(32, 32), 64, 0, stream>>>(qrope, kqf, ksf, qkf);
  kattn<<<dim3(NCH, KVH_, B_), 256, 0, stream>>>(kvc, kvs, btab, ctx, qrope, qkf, vqf, vsf, pm, pl, pacc);
  kcomb_quant<<<32, 256, 0, stream>>>(pm, pl, pacc, aqT, asb);
  kprep_a<<<64, 256, 0, stream>>>(aqT, af);
  kgemm_mfma<<<dim3(HID_ / 128, KS_), 256, 0, stream>>>(ow, af, Yp, HID_);
  kfinal<<<512, 256, 0, stream>>>(Yp, asb, owsc, out);
}

// Round 3
// 258.945 us; speedup vs baseline: 1.2943x; 1.2943x over previous
//
#include <hip/hip_runtime.h>
#include <math.h>

#define B_    32
#define H_    32
#define KVH_  8
#define D_    128
#define HID_  4096
#define TPB_  64
#define MB_   32
#define G_    4
#define RQKV  6144
#define KS_   16
#define NCH   32
#define SCALING 0.08838834764831845f

typedef __attribute__((ext_vector_type(8))) short short8_t;
typedef __attribute__((ext_vector_type(16))) float f32x16;

__device__ __forceinline__ unsigned int pk2(float lo, float hi) {
  return (__float_as_uint(hi) & 0xffff0000u) | (__float_as_uint(lo) >> 16);
}

// ---------- build X B-fragments from hidden_q (int [32][4096]) ----------
__global__ __launch_bounds__(256) void kprep_x(const int* __restrict__ src, uint4* __restrict__ frag) {
  int gid = blockIdx.x * 256 + threadIdx.x;   // 256 tiles * 64 lanes
  int l = gid & 63, t = gid >> 6;
  int bb = l & 31;
  int k0 = t * 16 + (l >> 5) * 8;
  const int* p = &src[(size_t)bb * HID_ + k0];
  int4 a = *(const int4*)p;
  int4 c = *(const int4*)(p + 4);
  uint4 o;
  o.x = pk2((float)a.x, (float)a.y);
  o.y = pk2((float)a.z, (float)a.w);
  o.z = pk2((float)c.x, (float)c.y);
  o.w = pk2((float)c.z, (float)c.w);
  frag[gid] = o;
}

// ---------- MFMA GEMM: Yp[ks][R][32] = W[R][4096] x X^T[4096][32] ----------
__global__ __launch_bounds__(256) void kgemm_mfma(const int* __restrict__ W, const uint4* __restrict__ xf,
                                                  float* __restrict__ Yp, int R) {
  int wave = threadIdx.x >> 6, lane = threadIdx.x & 63;
  int j0 = blockIdx.x * 128 + wave * 32;
  int row = lane & 31, hi = lane >> 5;
  int kbase = blockIdx.y * 256;
  f32x16 acc;
#pragma unroll
  for (int i = 0; i < 16; i++) acc[i] = 0.f;
  const int* wp = &W[(size_t)(j0 + row) * HID_ + kbase + hi * 8];
  const uint4* xp = &xf[(size_t)(kbase >> 4) * 64 + lane];
#pragma unroll
  for (int t = 0; t < 16; t++) {
    int4 wa = *(const int4*)(wp + t * 16);
    int4 wb = *(const int4*)(wp + t * 16 + 4);
    uint4 aw;
    aw.x = pk2((float)wa.x, (float)wa.y);
    aw.y = pk2((float)wa.z, (float)wa.w);
    aw.z = pk2((float)wb.x, (float)wb.y);
    aw.w = pk2((float)wb.z, (float)wb.w);
    uint4 bw = xp[t * 64];
    acc = __builtin_amdgcn_mfma_f32_32x32x16_bf16(__builtin_bit_cast(short8_t, aw),
                                                  __builtin_bit_cast(short8_t, bw), acc, 0, 0, 0);
  }
  int col = lane & 31;
#pragma unroll
  for (int r = 0; r < 16; r++) {
    int rowout = (r & 3) + 8 * (r >> 2) + 4 * hi;
    Yp[((size_t)blockIdx.y * R + j0 + rowout) * 32 + col] = acc[r];
  }
}

// ---------- reduce partials + scales + RoPE + fresh k/v quant ----------
__global__ __launch_bounds__(128) void kpost_qkv(const float* __restrict__ Yp, const float* __restrict__ hs,
                                                 const float* __restrict__ wsc, const int* __restrict__ ctx,
                                                 float* __restrict__ qrope, int* __restrict__ kqf,
                                                 int* __restrict__ vqf, float* __restrict__ ksf,
                                                 float* __restrict__ vsf) {
  int r = blockIdx.x;      // 0..47
  int b = blockIdx.y;
  int d = threadIdx.x;     // 0..127
  int j = r * 128 + d;
  float v = 0.f;
#pragma unroll
  for (int ks = 0; ks < KS_; ks++) v += Yp[((size_t)ks * RQKV + j) * 32 + b];
  v *= hs[b] * wsc[j];
  __shared__ float x[128];
  __shared__ float red[2];
  x[d] = v;
  __syncthreads();
  int pos = ctx[b];
  float val;
  if (r < 40) {
    int i = d & 63;
    float f = powf(10000.f, -(float)i * (1.f / 64.f));
    float ang = (float)pos * f;
    float sv, cv;
    sincosf(ang, &sv, &cv);
    float xa = x[i], xb = x[i + 64];
    val = (d < 64) ? (xa * cv - xb * sv) : (xb * cv + xa * sv);
  } else {
    val = v;
  }
  if (r < 32) { qrope[((size_t)b * H_ + r) * D_ + d] = val; return; }
  float a = fabsf(val);
#pragma unroll
  for (int off = 32; off; off >>= 1) a = fmaxf(a, __shfl_xor(a, off));
  if ((d & 63) == 0) red[d >> 6] = a;
  __syncthreads();
  float mx = fmaxf(red[0], red[1]);
  float sc = fmaxf(mx, 1e-6f) * (1.f / 127.f);
  float qv = rintf(val / sc);
  qv = fminf(fmaxf(qv, -127.f), 127.f);
  int kvh = (r - 32) & 7;
  if (r < 40) {
    kqf[((size_t)b * KVH_ + kvh) * D_ + d] = (int)qv;
    if (d == 0) ksf[b * KVH_ + kvh] = sc;
  } else {
    vqf[((size_t)b * KVH_ + kvh) * D_ + d] = (int)qv;
    if (d == 0) vsf[b * KVH_ + kvh] = sc;
  }
}

// ---------- fresh-token score ----------
__global__ __launch_bounds__(64) void kfresh_score(const float* __restrict__ qrope, const int* __restrict__ kqf,
                                                   const float* __restrict__ ksf, float* __restrict__ qkf) {
  int h = blockIdx.x, b = blockIdx.y, l = threadIdx.x;
  int kvh = h >> 2;
  const float* q = &qrope[((size_t)b * H_ + h) * D_];
  const int* kk = &kqf[((size_t)b * KVH_ + kvh) * D_];
  float s = q[l] * (float)kk[l] + q[l + 64] * (float)kk[l + 64];
#pragma unroll
  for (int off = 32; off; off >>= 1) s += __shfl_xor(s, off);
  if (l == 0) qkf[b * H_ + h] = s * ksf[b * KVH_ + kvh] * SCALING;
}

// ---------- attention: one 64-token cache block per workgroup ----------
__global__ __launch_bounds__(256) void kattn(const int* __restrict__ kvc, const float* __restrict__ kvs,
                                             const int* __restrict__ btab, const int* __restrict__ ctx,
                                             const float* __restrict__ qrope, const float* __restrict__ qkf,
                                             const int* __restrict__ vqf, const float* __restrict__ vsf,
                                             float* __restrict__ pm, float* __restrict__ pl,
                                             float* __restrict__ pacc) {
  int cb = blockIdx.x, kvh = blockIdx.y, b = blockIdx.z;
  int tid = threadIdx.x;
  int pos = ctx[b];
  size_t pbase = ((size_t)(b * KVH_ + kvh) * NCH + cb) * G_;
  if (cb * 64 > pos) {
    if (tid < 4) { pm[pbase + tid] = -1e30f; pl[pbase + tid] = 0.f; }
    return;
  }
  __shared__ __align__(16) float qlds[512];   // XOR-swizzled: w ^ (((w>>5)&3)<<2)
  __shared__ float sls[4][64];
  __shared__ float pls[4][64];
  __shared__ float hb[4][128];
  int blk = btab[b * MB_ + cb];

  for (int i = tid; i < 512; i += 256) {
    int sw = i ^ (((i >> 5) & 3) << 2);
    qlds[sw] = qrope[((size_t)b * H_ + kvh * G_) * D_ + i];
  }
  __syncthreads();

  // ---- phase 1: QK^T, 4 lanes per token ----
  {
    int t = tid >> 2, c = tid & 3;
    const int* krow = &kvc[(((size_t)(blk * 2 + 0) * KVH_ + kvh) * TPB_ + t) * D_ + c * 32];
    float kv[32];
#pragma unroll
    for (int i = 0; i < 8; i++) {
      int4 k4 = *(const int4*)&krow[i * 4];
      kv[i * 4 + 0] = (float)k4.x;
      kv[i * 4 + 1] = (float)k4.y;
      kv[i * 4 + 2] = (float)k4.z;
      kv[i * 4 + 3] = (float)k4.w;
    }
    float ksc = kvs[((size_t)(blk * 2 + 0) * KVH_ + kvh) * TPB_ + t] * SCALING;
#pragma unroll
    for (int g = 0; g < 4; g++) {
      int base = g * 128 + c * 32;
      float dot = 0.f;
#pragma unroll
      for (int i = 0; i < 8; i++) {
        float4 q4 = *(const float4*)&qlds[(base + i * 4) ^ (c << 2)];
        dot += kv[i * 4 + 0] * q4.x + kv[i * 4 + 1] * q4.y +
               kv[i * 4 + 2] * q4.z + kv[i * 4 + 3] * q4.w;
      }
      dot += __shfl_xor(dot, 1);
      dot += __shfl_xor(dot, 2);
      if (c == 0) sls[g][t] = dot * ksc;
    }
  }
  __syncthreads();

  // ---- phase 2: softmax, one wave per head ----
  {
    int g = tid >> 6, t = tid & 63;
    int s = cb * 64 + t;
    float sc = sls[g][t];
    if (s == pos) sc = qkf[b * H_ + kvh * G_ + g];
    else if (s > pos) sc = -1e30f;
    float m = sc;
#pragma unroll
    for (int off = 32; off; off >>= 1) m = fmaxf(m, __shfl_xor(m, off));
    float p = (s <= pos) ? expf(sc - m) : 0.f;
    float l = p;
#pragma unroll
    for (int off = 32; off; off >>= 1) l += __shfl_xor(l, off);
    if (t == 0) { pm[pbase + g] = m; pl[pbase + g] = l; }
    float vsc = (s == pos) ? vsf[b * KVH_ + kvh]
                           : kvs[((size_t)(blk * 2 + 1) * KVH_ + kvh) * TPB_ + t];
    pls[g][t] = p * vsc;
  }
  __syncthreads();

  // ---- phase 3: PV, lanes = d ----
  {
    int d = tid & 127, half = tid >> 7;
    const int* vbase = &kvc[(((size_t)(blk * 2 + 1) * KVH_ + kvh) * TPB_) * D_ + d];
    int freshT = pos - cb * 64;   // in [0,63] iff fresh token in this block
    float a0 = 0.f, a1 = 0.f, a2 = 0.f, a3 = 0.f;
    for (int tt = half; tt < 64; tt += 2) {
      const int* vr = (tt == freshT) ? &vqf[(size_t)(b * KVH_ + kvh) * D_ + d] : vbase + tt * D_;
      float vv = (float)*vr;
      a0 = fmaf(pls[0][tt], vv, a0);
      a1 = fmaf(pls[1][tt], vv, a1);
      a2 = fmaf(pls[2][tt], vv, a2);
      a3 = fmaf(pls[3][tt], vv, a3);
    }
    __syncthreads();
    if (half == 1) { hb[0][d] = a0; hb[1][d] = a1; hb[2][d] = a2; hb[3][d] = a3; }
    __syncthreads();
    if (half == 0) {
      float* pa = &pacc[pbase * D_];
      pa[0 * D_ + d] = a0 + hb[0][d];
      pa[1 * D_ + d] = a1 + hb[1][d];
      pa[2 * D_ + d] = a2 + hb[2][d];
      pa[3 * D_ + d] = a3 + hb[3][d];
    }
  }
}

// ---------- combine chunks (parallel over 8 slices per batch) ----------
__global__ __launch_bounds__(256) void kcomb1(const float* __restrict__ pm, const float* __restrict__ pl,
                                              const float* __restrict__ pacc, float* __restrict__ attnT,
                                              float* __restrict__ amaxp) {
  int sl = blockIdx.x, b = blockIdx.y;
  int tid = threadIdx.x;
  __shared__ float wch[32][32];   // [kvh*4+g][ch]
  __shared__ float invL[32];
  __shared__ float rbuf[4];
  if (tid < 32) {
    int kvh = tid >> 2, g = tid & 3;
    float M = -1e30f;
    float m[NCH];
#pragma unroll
    for (int ch = 0; ch < NCH; ch++) {
      m[ch] = pm[((size_t)(b * KVH_ + kvh) * NCH + ch) * G_ + g];
      M = fmaxf(M, m[ch]);
    }
    float L = 0.f;
#pragma unroll
    for (int ch = 0; ch < NCH; ch++) {
      float w = expf(m[ch] - M);
      wch[tid][ch] = w;
      L += pl[((size_t)(b * KVH_ + kvh) * NCH + ch) * G_ + g] * w;
    }
    invL[tid] = 1.f / L;
  }
  __syncthreads();
  float amax = 0.f;
#pragma unroll
  for (int rep = 0; rep < 2; rep++) {
    int j = sl * 512 + rep * 256 + tid;
    int h = j >> 7, d = j & 127;
    int kvh = h >> 2, g = h & 3;
    int hh = kvh * 4 + g;
    float v = 0.f;
#pragma unroll 8
    for (int ch = 0; ch < NCH; ch++) {
      float w = wch[hh][ch];
      if (w != 0.f)
        v += pacc[(((size_t)(b * KVH_ + kvh) * NCH + ch) * G_ + g) * D_ + d] * w;
    }
    v *= invL[hh];
    attnT[(size_t)j * 32 + b] = v;
    amax = fmaxf(amax, fabsf(v));
  }
#pragma unroll
  for (int off = 32; off; off >>= 1) amax = fmaxf(amax, __shfl_xor(amax, off));
  if ((tid & 63) == 0) rbuf[tid >> 6] = amax;
  __syncthreads();
  if (tid == 0)
    amaxp[b * 8 + sl] = fmaxf(fmaxf(rbuf[0], rbuf[1]), fmaxf(rbuf[2], rbuf[3]));
}

// ---------- quantize attn + build MFMA fragments + asb ----------
__global__ __launch_bounds__(256) void kcomb2(const float* __restrict__ attnT, const float* __restrict__ amaxp,
                                              uint4* __restrict__ frag, float* __restrict__ asb) {
  int gid = blockIdx.x * 256 + threadIdx.x;   // 16384
  int l = gid & 63, t = gid >> 6;
  int bb = l & 31;
  int k0 = t * 16 + (l >> 5) * 8;
  float amax = 0.f;
#pragma unroll
  for (int sl = 0; sl < 8; sl++) amax = fmaxf(amax, amaxp[bb * 8 + sl]);
  float as = fmaxf(amax, 1e-6f) * (1.f / 127.f);
  float inv = 1.f / as;
  if (gid < 32) asb[gid] = as;
  float v[8];
#pragma unroll
  for (int e = 0; e < 8; e++) {
    float q = rintf(attnT[(size_t)(k0 + e) * 32 + bb] * inv);
    v[e] = fminf(fmaxf(q, -127.f), 127.f);
  }
  uint4 o;
  o.x = pk2(v[0], v[1]);
  o.y = pk2(v[2], v[3]);
  o.z = pk2(v[4], v[5]);
  o.w = pk2(v[6], v[7]);
  frag[gid] = o;
}

// ---------- reduce o-proj partials + final scales ----------
__global__ __launch_bounds__(256) void kfinal(const float* __restrict__ Yp, const float* __restrict__ asb,
                                              const float* __restrict__ owsc, float* __restrict__ out) {
  int gid = blockIdx.x * 256 + threadIdx.x;   // 131072
  int i = gid & (HID_ - 1), bb = gid >> 12;
  float v = 0.f;
#pragma unroll
  for (int ks = 0; ks < KS_; ks++) v += Yp[((size_t)ks * HID_ + i) * 32 + bb];
  out[(size_t)bb * HID_ + i] = v * asb[bb] * owsc[i];
}

extern "C" void kernel_launch(void* const* d_in, const int* in_sizes, int n_in,
                              void* d_out, int out_size, void* d_ws, size_t ws_size,
                              hipStream_t stream) {
  const int*   hq    = (const int*)d_in[0];
  const float* hs    = (const float*)d_in[1];
  const int*   qkvw  = (const int*)d_in[2];
  const float* qkvws = (const float*)d_in[3];
  const int*   ow    = (const int*)d_in[4];
  const float* owsc  = (const float*)d_in[5];
  const int*   kvc   = (const int*)d_in[6];
  const float* kvs   = (const float*)d_in[7];
  const int*   btab  = (const int*)d_in[8];
  const int*   ctx   = (const int*)d_in[9];
  float* out = (float*)d_out;

  char* ws = (char*)d_ws;
  uint4* xf    = (uint4*)(ws);                 //   262144
  uint4* af    = (uint4*)(ws + 262144);        //   262144
  float* Yp    = (float*)(ws + 524288);        // 12582912
  float* qrope = (float*)(ws + 13107200);      //   524288
  int*   kqf   = (int*)  (ws + 13631488);      //   131072
  int*   vqf   = (int*)  (ws + 13762560);      //   131072
  float* ksf   = (float*)(ws + 13893632);      //     1024
  float* vsf   = (float*)(ws + 13894656);      //     1024
  float* qkf   = (float*)(ws + 13895680);      //     4096
  float* pm    = (float*)(ws + 13899776);      //   131072
  float* pl    = (float*)(ws + 14030848);      //   131072
  float* pacc  = (float*)(ws + 14161920);      // 16777216
  float* attnT = (float*)(ws + 30939136);      //   524288
  float* amaxp = (float*)(ws + 31463424);      //     1024
  float* asb   = (float*)(ws + 31464448);      //      128

  kprep_x<<<64, 256, 0, stream>>>(hq, xf);
  kgemm_mfma<<<dim3(RQKV / 128, KS_), 256, 0, stream>>>(qkvw, xf, Yp, RQKV);
  kpost_qkv<<<dim3(48, 32), 128, 0, stream>>>(Yp, hs, qkvws, ctx, qrope, kqf, vqf, ksf, vsf);
  kfresh_score<<<dim3(32, 32), 64, 0, stream>>>(qrope, kqf, ksf, qkf);
  kattn<<<dim3(NCH, KVH_, B_), 256, 0, stream>>>(kvc, kvs, btab, ctx, qrope, qkf, vqf, vsf, pm, pl, pacc);
  kcomb1<<<dim3(8, B_), 256, 0, stream>>>(pm, pl, pacc, attnT, amaxp);
  kcomb2<<<64, 256, 0, stream>>>(attnT, amaxp, af, asb);
  kgemm_mfma<<<dim3(HID_ / 128, KS_), 256, 0, stream>>>(ow, af, Yp, HID_);
  kfinal<<<512, 256, 0, stream>>>(Yp, asb, owsc, out);
}

// Round 4
// 246.166 us; speedup vs baseline: 1.3615x; 1.0519x over previous
//
#include <hip/hip_runtime.h>
#include <math.h>

#define B_    32
#define H_    32
#define KVH_  8
#define D_    128
#define HID_  4096
#define TPB_  64
#define MB_   32
#define G_    4
#define RQKV  6144
#define KS_   16
#define NCH   32
#define SCALING 0.08838834764831845f

typedef __attribute__((ext_vector_type(8))) short short8_t;
typedef __attribute__((ext_vector_type(16))) float f32x16;

__device__ __forceinline__ unsigned int pk2(float lo, float hi) {
  return (__float_as_uint(hi) & 0xffff0000u) | (__float_as_uint(lo) >> 16);
}

// ---------- build X B-fragments from hidden_q (int [32][4096]) ----------
__global__ __launch_bounds__(256) void kprep_x(const int* __restrict__ src, uint4* __restrict__ frag) {
  int gid = blockIdx.x * 256 + threadIdx.x;
  int l = gid & 63, t = gid >> 6;
  int bb = l & 31;
  int k0 = t * 16 + (l >> 5) * 8;
  const int* p = &src[(size_t)bb * HID_ + k0];
  int4 a = *(const int4*)p;
  int4 c = *(const int4*)(p + 4);
  uint4 o;
  o.x = pk2((float)a.x, (float)a.y);
  o.y = pk2((float)a.z, (float)a.w);
  o.z = pk2((float)c.x, (float)c.y);
  o.w = pk2((float)c.z, (float)c.w);
  frag[gid] = o;
}

// ---------- MFMA GEMM: Yp[ks][R][32] = W[R][4096] x X^T[4096][32] ----------
__global__ __launch_bounds__(256) void kgemm_mfma(const int* __restrict__ W, const uint4* __restrict__ xf,
                                                  float* __restrict__ Yp, int R) {
  int wave = threadIdx.x >> 6, lane = threadIdx.x & 63;
  int j0 = blockIdx.x * 128 + wave * 32;
  int row = lane & 31, hi = lane >> 5;
  int kbase = blockIdx.y * 256;
  f32x16 acc;
#pragma unroll
  for (int i = 0; i < 16; i++) acc[i] = 0.f;
  const int* wp = &W[(size_t)(j0 + row) * HID_ + kbase + hi * 8];
  const uint4* xp = &xf[(size_t)(kbase >> 4) * 64 + lane];
#pragma unroll
  for (int t = 0; t < 16; t++) {
    int4 wa = *(const int4*)(wp + t * 16);
    int4 wb = *(const int4*)(wp + t * 16 + 4);
    uint4 aw;
    aw.x = pk2((float)wa.x, (float)wa.y);
    aw.y = pk2((float)wa.z, (float)wa.w);
    aw.z = pk2((float)wb.x, (float)wb.y);
    aw.w = pk2((float)wb.z, (float)wb.w);
    uint4 bw = xp[t * 64];
    acc = __builtin_amdgcn_mfma_f32_32x32x16_bf16(__builtin_bit_cast(short8_t, aw),
                                                  __builtin_bit_cast(short8_t, bw), acc, 0, 0, 0);
  }
  int col = lane & 31;
#pragma unroll
  for (int r = 0; r < 16; r++) {
    int rowout = (r & 3) + 8 * (r >> 2) + 4 * hi;
    Yp[((size_t)blockIdx.y * R + j0 + rowout) * 32 + col] = acc[r];
  }
}

// ---------- coalesced reduce over k-slices + LDS transpose: Yp -> outT[b][j]*sb[b]*sj[j] ----------
__global__ __launch_bounds__(256) void kred(const float* __restrict__ Yp, const float* __restrict__ sb,
                                            const float* __restrict__ sj, float* __restrict__ outT, int R) {
  int tid = threadIdx.x;
  int j0 = blockIdx.x * 32;
  __shared__ float lds[32 * 33];
  float acc[4] = {0.f, 0.f, 0.f, 0.f};
  for (int ks = 0; ks < KS_; ks++) {
    const float* p = &Yp[(size_t)ks * R * 32 + j0 * 32];
#pragma unroll
    for (int e = 0; e < 4; e++) acc[e] += p[e * 256 + tid];
  }
#pragma unroll
  for (int e = 0; e < 4; e++) {
    int f = e * 256 + tid;
    int jl = f >> 5, b = f & 31;
    lds[b * 33 + jl] = acc[e];
  }
  __syncthreads();
#pragma unroll
  for (int e = 0; e < 4; e++) {
    int f = e * 256 + tid;
    int b = f >> 5, jl = f & 31;
    outT[(size_t)b * R + j0 + jl] = lds[b * 33 + jl] * sb[b] * sj[j0 + jl];
  }
}

// ---------- RoPE + fresh k/v quant (reads coalesced YsT[b][j]) ----------
__global__ __launch_bounds__(128) void kpost_qkv(const float* __restrict__ YsT, const int* __restrict__ ctx,
                                                 float* __restrict__ qrope, int* __restrict__ kqf,
                                                 int* __restrict__ vqf, float* __restrict__ ksf,
                                                 float* __restrict__ vsf) {
  int r = blockIdx.x;      // 0..47
  int b = blockIdx.y;
  int d = threadIdx.x;     // 0..127
  float v = YsT[(size_t)b * RQKV + r * 128 + d];
  __shared__ float x[128];
  __shared__ float red[2];
  x[d] = v;
  __syncthreads();
  int pos = ctx[b];
  float val;
  if (r < 40) {
    int i = d & 63;
    float f = powf(10000.f, -(float)i * (1.f / 64.f));
    float ang = (float)pos * f;
    float sv, cv;
    sincosf(ang, &sv, &cv);
    float xa = x[i], xb = x[i + 64];
    val = (d < 64) ? (xa * cv - xb * sv) : (xb * cv + xa * sv);
  } else {
    val = v;
  }
  if (r < 32) { qrope[((size_t)b * H_ + r) * D_ + d] = val; return; }
  float a = fabsf(val);
#pragma unroll
  for (int off = 32; off; off >>= 1) a = fmaxf(a, __shfl_xor(a, off));
  if ((d & 63) == 0) red[d >> 6] = a;
  __syncthreads();
  float mx = fmaxf(red[0], red[1]);
  float sc = fmaxf(mx, 1e-6f) * (1.f / 127.f);
  float qv = rintf(val / sc);
  qv = fminf(fmaxf(qv, -127.f), 127.f);
  int kvh = (r - 32) & 7;
  if (r < 40) {
    kqf[((size_t)b * KVH_ + kvh) * D_ + d] = (int)qv;
    if (d == 0) ksf[b * KVH_ + kvh] = sc;
  } else {
    vqf[((size_t)b * KVH_ + kvh) * D_ + d] = (int)qv;
    if (d == 0) vsf[b * KVH_ + kvh] = sc;
  }
}

// ---------- fresh-token score ----------
__global__ __launch_bounds__(64) void kfresh_score(const float* __restrict__ qrope, const int* __restrict__ kqf,
                                                   const float* __restrict__ ksf, float* __restrict__ qkf) {
  int h = blockIdx.x, b = blockIdx.y, l = threadIdx.x;
  int kvh = h >> 2;
  const float* q = &qrope[((size_t)b * H_ + h) * D_];
  const int* kk = &kqf[((size_t)b * KVH_ + kvh) * D_];
  float s = q[l] * (float)kk[l] + q[l + 64] * (float)kk[l + 64];
#pragma unroll
  for (int off = 32; off; off >>= 1) s += __shfl_xor(s, off);
  if (l == 0) qkf[b * H_ + h] = s * ksf[b * KVH_ + kvh] * SCALING;
}

// ---------- attention: one 64-token cache block per workgroup ----------
__global__ __launch_bounds__(256) void kattn(const int* __restrict__ kvc, const float* __restrict__ kvs,
                                             const int* __restrict__ btab, const int* __restrict__ ctx,
                                             const float* __restrict__ qrope, const float* __restrict__ qkf,
                                             const int* __restrict__ vqf, const float* __restrict__ vsf,
                                             float* __restrict__ pm, float* __restrict__ pl,
                                             float* __restrict__ pacc) {
  int cb = blockIdx.x, kvh = blockIdx.y, b = blockIdx.z;
  int tid = threadIdx.x;
  int pos = ctx[b];
  size_t pbase = ((size_t)(b * KVH_ + kvh) * NCH + cb) * G_;
  if (cb * 64 > pos) {
    if (tid < 4) { pm[pbase + tid] = -1e30f; pl[pbase + tid] = 0.f; }
    return;
  }
  __shared__ __align__(16) float qlds[512];   // XOR-swizzled: w ^ (((w>>5)&3)<<2)
  __shared__ float sls[4][64];
  __shared__ float pls[4][64];
  __shared__ float hb[4][128];
  int blk = btab[b * MB_ + cb];

  for (int i = tid; i < 512; i += 256) {
    int sw = i ^ (((i >> 5) & 3) << 2);
    qlds[sw] = qrope[((size_t)b * H_ + kvh * G_) * D_ + i];
  }
  __syncthreads();

  // ---- phase 1: QK^T, 4 lanes per token ----
  {
    int t = tid >> 2, c = tid & 3;
    const int* krow = &kvc[(((size_t)(blk * 2 + 0) * KVH_ + kvh) * TPB_ + t) * D_ + c * 32];
    float kv[32];
#pragma unroll
    for (int i = 0; i < 8; i++) {
      int4 k4 = *(const int4*)&krow[i * 4];
      kv[i * 4 + 0] = (float)k4.x;
      kv[i * 4 + 1] = (float)k4.y;
      kv[i * 4 + 2] = (float)k4.z;
      kv[i * 4 + 3] = (float)k4.w;
    }
    float ksc = kvs[((size_t)(blk * 2 + 0) * KVH_ + kvh) * TPB_ + t] * SCALING;
#pragma unroll
    for (int g = 0; g < 4; g++) {
      int base = g * 128 + c * 32;
      float dot = 0.f;
#pragma unroll
      for (int i = 0; i < 8; i++) {
        float4 q4 = *(const float4*)&qlds[(base + i * 4) ^ (c << 2)];
        dot += kv[i * 4 + 0] * q4.x + kv[i * 4 + 1] * q4.y +
               kv[i * 4 + 2] * q4.z + kv[i * 4 + 3] * q4.w;
      }
      dot += __shfl_xor(dot, 1);
      dot += __shfl_xor(dot, 2);
      if (c == 0) sls[g][t] = dot * ksc;
    }
  }
  __syncthreads();

  // ---- phase 2: softmax, one wave per head ----
  {
    int g = tid >> 6, t = tid & 63;
    int s = cb * 64 + t;
    float sc = sls[g][t];
    if (s == pos) sc = qkf[b * H_ + kvh * G_ + g];
    else if (s > pos) sc = -1e30f;
    float m = sc;
#pragma unroll
    for (int off = 32; off; off >>= 1) m = fmaxf(m, __shfl_xor(m, off));
    float p = (s <= pos) ? expf(sc - m) : 0.f;
    float l = p;
#pragma unroll
    for (int off = 32; off; off >>= 1) l += __shfl_xor(l, off);
    if (t == 0) { pm[pbase + g] = m; pl[pbase + g] = l; }
    float vsc = (s == pos) ? vsf[b * KVH_ + kvh]
                           : kvs[((size_t)(blk * 2 + 1) * KVH_ + kvh) * TPB_ + t];
    pls[g][t] = p * vsc;
  }
  __syncthreads();

  // ---- phase 3: PV, lanes = d ----
  {
    int d = tid & 127, half = tid >> 7;
    const int* vbase = &kvc[(((size_t)(blk * 2 + 1) * KVH_ + kvh) * TPB_) * D_ + d];
    int freshT = pos - cb * 64;
    float a0 = 0.f, a1 = 0.f, a2 = 0.f, a3 = 0.f;
    for (int tt = half; tt < 64; tt += 2) {
      const int* vr = (tt == freshT) ? &vqf[(size_t)(b * KVH_ + kvh) * D_ + d] : vbase + tt * D_;
      float vv = (float)*vr;
      a0 = fmaf(pls[0][tt], vv, a0);
      a1 = fmaf(pls[1][tt], vv, a1);
      a2 = fmaf(pls[2][tt], vv, a2);
      a3 = fmaf(pls[3][tt], vv, a3);
    }
    __syncthreads();
    if (half == 1) { hb[0][d] = a0; hb[1][d] = a1; hb[2][d] = a2; hb[3][d] = a3; }
    __syncthreads();
    if (half == 0) {
      float* pa = &pacc[pbase * D_];
      pa[0 * D_ + d] = a0 + hb[0][d];
      pa[1 * D_ + d] = a1 + hb[1][d];
      pa[2 * D_ + d] = a2 + hb[2][d];
      pa[3 * D_ + d] = a3 + hb[3][d];
    }
  }
}

// ---------- combine chunks -> attnB[b][j] (coalesced) + partial amax ----------
__global__ __launch_bounds__(256) void kcomb1(const float* __restrict__ pm, const float* __restrict__ pl,
                                              const float* __restrict__ pacc, float* __restrict__ attnB,
                                              float* __restrict__ amaxp) {
  int sl = blockIdx.x, b = blockIdx.y;
  int tid = threadIdx.x;
  __shared__ float wch[32][32];
  __shared__ float invL[32];
  __shared__ float rbuf[4];
  if (tid < 32) {
    int kvh = tid >> 2, g = tid & 3;
    float M = -1e30f;
    float m[NCH];
#pragma unroll
    for (int ch = 0; ch < NCH; ch++) {
      m[ch] = pm[((size_t)(b * KVH_ + kvh) * NCH + ch) * G_ + g];
      M = fmaxf(M, m[ch]);
    }
    float L = 0.f;
#pragma unroll
    for (int ch = 0; ch < NCH; ch++) {
      float w = expf(m[ch] - M);
      wch[tid][ch] = w;
      L += pl[((size_t)(b * KVH_ + kvh) * NCH + ch) * G_ + g] * w;
    }
    invL[tid] = 1.f / L;
  }
  __syncthreads();
  float amax = 0.f;
#pragma unroll
  for (int rep = 0; rep < 2; rep++) {
    int j = sl * 512 + rep * 256 + tid;
    int h = j >> 7, d = j & 127;
    int kvh = h >> 2, g = h & 3;
    int hh = kvh * 4 + g;
    float v = 0.f;
#pragma unroll 8
    for (int ch = 0; ch < NCH; ch++) {
      float w = wch[hh][ch];
      if (w != 0.f)
        v += pacc[(((size_t)(b * KVH_ + kvh) * NCH + ch) * G_ + g) * D_ + d] * w;
    }
    v *= invL[hh];
    attnB[(size_t)b * (H_ * D_) + j] = v;
    amax = fmaxf(amax, fabsf(v));
  }
#pragma unroll
  for (int off = 32; off; off >>= 1) amax = fmaxf(amax, __shfl_xor(amax, off));
  if ((tid & 63) == 0) rbuf[tid >> 6] = amax;
  __syncthreads();
  if (tid == 0)
    amaxp[b * 8 + sl] = fmaxf(fmaxf(rbuf[0], rbuf[1]), fmaxf(rbuf[2], rbuf[3]));
}

// ---------- quantize attn + build MFMA fragments + asb ----------
__global__ __launch_bounds__(256) void kcomb2(const float* __restrict__ attnB, const float* __restrict__ amaxp,
                                              uint4* __restrict__ frag, float* __restrict__ asb) {
  int gid = blockIdx.x * 256 + threadIdx.x;   // 16384
  int l = gid & 63, t = gid >> 6;
  int bb = l & 31;
  int k0 = t * 16 + (l >> 5) * 8;
  float amax = 0.f;
#pragma unroll
  for (int sl = 0; sl < 8; sl++) amax = fmaxf(amax, amaxp[bb * 8 + sl]);
  float as = fmaxf(amax, 1e-6f) * (1.f / 127.f);
  float inv = 1.f / as;
  if (gid < 32) asb[gid] = as;
  const float* src = &attnB[(size_t)bb * (H_ * D_) + k0];
  float4 s0 = *(const float4*)src;
  float4 s1 = *(const float4*)(src + 4);
  float v[8];
  v[0] = s0.x; v[1] = s0.y; v[2] = s0.z; v[3] = s0.w;
  v[4] = s1.x; v[5] = s1.y; v[6] = s1.z; v[7] = s1.w;
#pragma unroll
  for (int e = 0; e < 8; e++) {
    float q = rintf(v[e] * inv);
    v[e] = fminf(fmaxf(q, -127.f), 127.f);
  }
  uint4 o;
  o.x = pk2(v[0], v[1]);
  o.y = pk2(v[2], v[3]);
  o.z = pk2(v[4], v[5]);
  o.w = pk2(v[6], v[7]);
  frag[gid] = o;
}

extern "C" void kernel_launch(void* const* d_in, const int* in_sizes, int n_in,
                              void* d_out, int out_size, void* d_ws, size_t ws_size,
                              hipStream_t stream) {
  const int*   hq    = (const int*)d_in[0];
  const float* hs    = (const float*)d_in[1];
  const int*   qkvw  = (const int*)d_in[2];
  const float* qkvws = (const float*)d_in[3];
  const int*   ow    = (const int*)d_in[4];
  const float* owsc  = (const float*)d_in[5];
  const int*   kvc   = (const int*)d_in[6];
  const float* kvs   = (const float*)d_in[7];
  const int*   btab  = (const int*)d_in[8];
  const int*   ctx   = (const int*)d_in[9];
  float* out = (float*)d_out;

  char* ws = (char*)d_ws;
  uint4* xf    = (uint4*)(ws);                 //   262144
  uint4* af    = (uint4*)(ws + 262144);        //   262144
  float* Yp    = (float*)(ws + 524288);        // 12582912
  float* YsT   = (float*)(ws + 13107200);      //   786432
  float* qrope = (float*)(ws + 13893632);      //   524288
  int*   kqf   = (int*)  (ws + 14417920);      //   131072
  int*   vqf   = (int*)  (ws + 14548992);      //   131072
  float* ksf   = (float*)(ws + 14680064);      //     1024
  float* vsf   = (float*)(ws + 14681088);      //     1024
  float* qkf   = (float*)(ws + 14682112);      //     4096
  float* pm    = (float*)(ws + 14686208);      //   131072
  float* pl    = (float*)(ws + 14817280);      //   131072
  float* pacc  = (float*)(ws + 14948352);      // 16777216
  float* attnB = (float*)(ws + 31725568);      //   524288
  float* amaxp = (float*)(ws + 32249856);      //     1024
  float* asb   = (float*)(ws + 32250880);      //      128

  kprep_x<<<64, 256, 0, stream>>>(hq, xf);
  kgemm_mfma<<<dim3(RQKV / 128, KS_), 256, 0, stream>>>(qkvw, xf, Yp, RQKV);
  kred<<<RQKV / 32, 256, 0, stream>>>(Yp, hs, qkvws, YsT, RQKV);
  kpost_qkv<<<dim3(48, 32), 128, 0, stream>>>(YsT, ctx, qrope, kqf, vqf, ksf, vsf);
  kfresh_score<<<dim3(32, 32), 64, 0, stream>>>(qrope, kqf, ksf, qkf);
  kattn<<<dim3(NCH, KVH_, B_), 256, 0, stream>>>(kvc, kvs, btab, ctx, qrope, qkf, vqf, vsf, pm, pl, pacc);
  kcomb1<<<dim3(8, B_), 256, 0, stream>>>(pm, pl, pacc, attnB, amaxp);
  kcomb2<<<64, 256, 0, stream>>>(attnB, amaxp, af, asb);
  kgemm_mfma<<<dim3(HID_ / 128, KS_), 256, 0, stream>>>(ow, af, Yp, HID_);
  kred<<<HID_ / 32, 256, 0, stream>>>(Yp, asb, owsc, out, HID_);
}